// Round 1
// baseline (351.603 us; speedup 1.0000x reference)
//
#include <hip/hip_runtime.h>

#define HD 16
#define DHEAD 64
#define DMODEL 1024
#define BB 2
#define SS 2048
#define MTOT (BB*SS)   // 4096

typedef float f32x4 __attribute__((ext_vector_type(4)));
typedef __bf16 bf16x8 __attribute__((ext_vector_type(8)));
typedef unsigned short u16x8 __attribute__((ext_vector_type(8)));

__device__ __forceinline__ unsigned short f2bf(float f) {
    unsigned int u = __builtin_bit_cast(unsigned int, f);
    unsigned int r = (u + 0x7fffu + ((u >> 16) & 1u)) >> 16;   // RNE
    return (unsigned short)r;
}

__device__ __forceinline__ bf16x8 ld8(const unsigned short* p) {
    u16x8 v = *reinterpret_cast<const u16x8*>(p);
    return __builtin_bit_cast(bf16x8, v);
}

__device__ __forceinline__ void gload_lds16(const unsigned short* g, unsigned short* l) {
    __builtin_amdgcn_global_load_lds(
        (const __attribute__((address_space(1))) void*)g,
        (__attribute__((address_space(3))) void*)l, 16, 0, 0);
}

// ---------------- fp32 -> bf16 convert ----------------
__global__ __launch_bounds__(256) void cvt_kernel(const float* __restrict__ in,
                                                  unsigned short* __restrict__ out, int n4) {
    int i = blockIdx.x * blockDim.x + threadIdx.x;
    if (i < n4) {
        float4 v = reinterpret_cast<const float4*>(in)[i];
        ushort4 o;
        o.x = f2bf(v.x); o.y = f2bf(v.y); o.z = f2bf(v.z); o.w = f2bf(v.w);
        reinterpret_cast<ushort4*>(out)[i] = o;
    }
}

// ---------------- GEMM core: C[128x128] = A[M,K] * B[N,K]^T ----------------
// LDS tile layout (elements): [kb(4)][row(128)][8], linear so global_load_lds works.
__device__ __forceinline__ void gemm_core(const unsigned short* __restrict__ A,
                                          const unsigned short* __restrict__ Bm,
                                          unsigned short* Als, unsigned short* Bls,
                                          int m0, int n0, int K, f32x4 acc[4][4]) {
    int t    = threadIdx.x;
    int wv   = t >> 6, lane = t & 63;
    int lrow = lane & 15, lgrp = lane >> 4;
    int wr   = wv >> 1, wc = wv & 1;
    int srow = t & 127, skb = t >> 7;   // staging: row, kb-base

    const unsigned short* Ag = A  + (size_t)(m0 + srow) * K + skb * 8;
    const unsigned short* Bg = Bm + (size_t)(n0 + srow) * K + skb * 8;

    for (int k0 = 0; k0 < K; k0 += 32) {
#pragma unroll
        for (int i = 0; i < 2; ++i) {
            gload_lds16(Ag + k0 + i * 16, Als + i * 2048 + wv * 512);
            gload_lds16(Bg + k0 + i * 16, Bls + i * 2048 + wv * 512);
        }
        __syncthreads();   // compiler drains vmcnt(0) before barrier

        bf16x8 af[4], bfr[4];
#pragma unroll
        for (int i = 0; i < 4; ++i) {
            af[i]  = ld8(&Als[lgrp * 1024 + (wr * 64 + i * 16 + lrow) * 8]);
            bfr[i] = ld8(&Bls[lgrp * 1024 + (wc * 64 + i * 16 + lrow) * 8]);
        }
#pragma unroll
        for (int mi = 0; mi < 4; ++mi)
#pragma unroll
            for (int ni = 0; ni < 4; ++ni)
                acc[mi][ni] = __builtin_amdgcn_mfma_f32_16x16x32_bf16(af[mi], bfr[ni], acc[mi][ni], 0, 0, 0);
        __syncthreads();   // protect LDS before next stage
    }
}

// ---------------- QKV projection (grid.z selects Q/K/V) ----------------
__global__ __launch_bounds__(256) void gemm_qkv(
    const unsigned short* __restrict__ xb,
    const unsigned short* __restrict__ Wqb, const unsigned short* __restrict__ Wkb,
    const unsigned short* __restrict__ Wvb,
    const float* __restrict__ bq, const float* __restrict__ bk, const float* __restrict__ bv,
    unsigned short* __restrict__ Qo, unsigned short* __restrict__ Ko, unsigned short* __restrict__ VTo) {
    __shared__ unsigned short Als[4096], Bls[4096];
    int z = blockIdx.z;
    const unsigned short* Bm = (z == 0) ? Wqb : (z == 1) ? Wkb : Wvb;
    const float* bias = (z == 0) ? bq : (z == 1) ? bk : bv;
    int m0 = blockIdx.y * 128, n0 = blockIdx.x * 128;

    f32x4 acc[4][4];
#pragma unroll
    for (int mi = 0; mi < 4; ++mi)
#pragma unroll
        for (int ni = 0; ni < 4; ++ni) acc[mi][ni] = (f32x4){0.f, 0.f, 0.f, 0.f};

    gemm_core(xb, Bm, Als, Bls, m0, n0, DMODEL, acc);

    int t = threadIdx.x, wv = t >> 6, lane = t & 63;
    int lrow = lane & 15, lgrp = lane >> 4;
    int wr = wv >> 1, wc = wv & 1;
    float scale = (z == 0) ? 0.125f : 1.0f;   // fold 1/sqrt(64) into Q

#pragma unroll
    for (int mi = 0; mi < 4; ++mi) {
#pragma unroll
        for (int ni = 0; ni < 4; ++ni) {
            int col = n0 + wc * 64 + ni * 16 + lrow;
            int h = col >> 6, dh = col & 63;
            float bi = bias[col];
#pragma unroll
            for (int r = 0; r < 4; ++r) {
                int row = m0 + wr * 64 + mi * 16 + lgrp * 4 + r;
                int b = row >> 11, s = row & 2047;
                unsigned short v16 = f2bf((acc[mi][ni][r] + bi) * scale);
                if (z == 2)
                    VTo[((size_t)((b * HD + h) * DHEAD + dh)) * SS + s] = v16;       // V transposed [bh][dh][s]
                else {
                    unsigned short* o = (z == 0) ? Qo : Ko;                           // [bh][s][dh]
                    o[((size_t)((b * HD + h) * SS + s)) * DHEAD + dh] = v16;
                }
            }
        }
    }
}

// ---------------- flash attention: 4 waves x 16 q-rows, 32-wide KV tiles ----------------
__global__ __launch_bounds__(256) void attn_kernel(
    const unsigned short* __restrict__ Qb, const unsigned short* __restrict__ Kb,
    const unsigned short* __restrict__ VTb, unsigned short* __restrict__ ctxo) {
    __shared__ unsigned short Pls[4][512];   // per-wave 16q x 32t bf16
    int bh = blockIdx.y;
    int q0 = blockIdx.x * 64;
    int t = threadIdx.x, wv = t >> 6, lane = t & 63;
    int lrow = lane & 15, lgrp = lane >> 4;
    const unsigned short* Qh  = Qb  + (size_t)bh * SS * DHEAD;
    const unsigned short* Kh  = Kb  + (size_t)bh * SS * DHEAD;
    const unsigned short* VTh = VTb + (size_t)bh * DHEAD * SS;
    int qr = q0 + wv * 16;

    // Q fragments (A operand), kept in registers for the whole kernel
    bf16x8 qf0 = ld8(&Qh[(qr + lrow) * DHEAD + lgrp * 8]);
    bf16x8 qf1 = ld8(&Qh[(qr + lrow) * DHEAD + 32 + lgrp * 8]);

    f32x4 o[4];
#pragma unroll
    for (int d4 = 0; d4 < 4; ++d4) o[d4] = (f32x4){0.f, 0.f, 0.f, 0.f};
    float mrun[4] = {-3e38f, -3e38f, -3e38f, -3e38f};
    float lrun[4] = {0.f, 0.f, 0.f, 0.f};

    for (int t0 = 0; t0 < SS; t0 += 32) {
        f32x4 sc[2];
#pragma unroll
        for (int tt = 0; tt < 2; ++tt) {
            bf16x8 kf0 = ld8(&Kh[(t0 + tt * 16 + lrow) * DHEAD + lgrp * 8]);
            bf16x8 kf1 = ld8(&Kh[(t0 + tt * 16 + lrow) * DHEAD + 32 + lgrp * 8]);
            f32x4 s4 = (f32x4){0.f, 0.f, 0.f, 0.f};
            s4 = __builtin_amdgcn_mfma_f32_16x16x32_bf16(qf0, kf0, s4, 0, 0, 0);
            s4 = __builtin_amdgcn_mfma_f32_16x16x32_bf16(qf1, kf1, s4, 0, 0, 0);
            sc[tt] = s4;   // D: col = t (lane&15), row = q (lgrp*4+r)
        }
        float al[4];
#pragma unroll
        for (int r = 0; r < 4; ++r) {
            float tm = fmaxf(sc[0][r], sc[1][r]);
            tm = fmaxf(tm, __shfl_xor(tm, 1));
            tm = fmaxf(tm, __shfl_xor(tm, 2));
            tm = fmaxf(tm, __shfl_xor(tm, 4));
            tm = fmaxf(tm, __shfl_xor(tm, 8));
            float mn = fmaxf(mrun[r], tm);
            al[r] = exp2f((mrun[r] - mn) * 1.44269504f);
            mrun[r] = mn;
        }
#pragma unroll
        for (int r = 0; r < 4; ++r) {
            float p0 = exp2f((sc[0][r] - mrun[r]) * 1.44269504f);
            float p1 = exp2f((sc[1][r] - mrun[r]) * 1.44269504f);
            sc[0][r] = p0; sc[1][r] = p1;
            float s = p0 + p1;
            s += __shfl_xor(s, 1); s += __shfl_xor(s, 2);
            s += __shfl_xor(s, 4); s += __shfl_xor(s, 8);
            lrun[r] = lrun[r] * al[r] + s;
        }
#pragma unroll
        for (int d4 = 0; d4 < 4; ++d4)
#pragma unroll
            for (int r = 0; r < 4; ++r) o[d4][r] *= al[r];

        // P -> LDS [q][t] so PV A-fragment reads are layout-correct
#pragma unroll
        for (int tt = 0; tt < 2; ++tt)
#pragma unroll
            for (int r = 0; r < 4; ++r)
                Pls[wv][(lgrp * 4 + r) * 32 + tt * 16 + lrow] = f2bf(sc[tt][r]);
        __syncthreads();
        bf16x8 pf = ld8(&Pls[wv][lrow * 32 + lgrp * 8]);
#pragma unroll
        for (int d4 = 0; d4 < 4; ++d4) {
            bf16x8 vf = ld8(&VTh[(d4 * 16 + lrow) * SS + t0 + lgrp * 8]);
            o[d4] = __builtin_amdgcn_mfma_f32_16x16x32_bf16(pf, vf, o[d4], 0, 0, 0);
        }
        __syncthreads();
    }

    int b = bh >> 4, h = bh & 15;
#pragma unroll
    for (int r = 0; r < 4; ++r) {
        float inv = 1.f / lrun[r];
        int s = qr + lgrp * 4 + r;
        size_t base = ((size_t)(b * SS + s)) * DMODEL + h * DHEAD;
#pragma unroll
        for (int d4 = 0; d4 < 4; ++d4)
            ctxo[base + d4 * 16 + lrow] = f2bf(o[d4][r] * inv);
    }
}

// ---------------- output projection -> fp32 proj ----------------
__global__ __launch_bounds__(256) void gemm_proj(
    const unsigned short* __restrict__ ctxb, const unsigned short* __restrict__ Wdb,
    const float* __restrict__ bd, float* __restrict__ proj) {
    __shared__ unsigned short Als[4096], Bls[4096];
    int m0 = blockIdx.y * 128, n0 = blockIdx.x * 128;
    f32x4 acc[4][4];
#pragma unroll
    for (int mi = 0; mi < 4; ++mi)
#pragma unroll
        for (int ni = 0; ni < 4; ++ni) acc[mi][ni] = (f32x4){0.f, 0.f, 0.f, 0.f};

    gemm_core(ctxb, Wdb, Als, Bls, m0, n0, DMODEL, acc);

    int t = threadIdx.x, wv = t >> 6, lane = t & 63;
    int lrow = lane & 15, lgrp = lane >> 4;
    int wr = wv >> 1, wc = wv & 1;
#pragma unroll
    for (int mi = 0; mi < 4; ++mi)
#pragma unroll
        for (int ni = 0; ni < 4; ++ni) {
            int col = n0 + wc * 64 + ni * 16 + lrow;
            float bi = bd[col];
#pragma unroll
            for (int r = 0; r < 4; ++r) {
                int row = m0 + wr * 64 + mi * 16 + lgrp * 4 + r;
                proj[(size_t)row * DMODEL + col] = acc[mi][ni][r] + bi;
            }
        }
}

// ---------------- LayerNorm over D=1024 ----------------
__global__ __launch_bounds__(256) void ln_kernel(const float* __restrict__ proj,
                                                 const float* __restrict__ g,
                                                 const float* __restrict__ bv,
                                                 float* __restrict__ out) {
    int row = blockIdx.x, t = threadIdx.x;
    float4 v = reinterpret_cast<const float4*>(proj + (size_t)row * DMODEL)[t];
    float s  = v.x + v.y + v.z + v.w;
    float s2 = v.x * v.x + v.y * v.y + v.z * v.z + v.w * v.w;
#pragma unroll
    for (int m = 1; m < 64; m <<= 1) { s += __shfl_xor(s, m); s2 += __shfl_xor(s2, m); }
    __shared__ float red[8];
    int wv = t >> 6, lane = t & 63;
    if (lane == 0) { red[wv] = s; red[wv + 4] = s2; }
    __syncthreads();
    s  = red[0] + red[1] + red[2] + red[3];
    s2 = red[4] + red[5] + red[6] + red[7];
    float mu  = s * (1.f / 1024.f);
    float var = s2 * (1.f / 1024.f) - mu * mu;
    float inv = rsqrtf(var + 1e-12f);
    float4 gv = reinterpret_cast<const float4*>(g)[t];
    float4 bb = reinterpret_cast<const float4*>(bv)[t];
    float4 ov;
    ov.x = (v.x - mu) * inv * gv.x + bb.x;
    ov.y = (v.y - mu) * inv * gv.y + bb.y;
    ov.z = (v.z - mu) * inv * gv.z + bb.z;
    ov.w = (v.w - mu) * inv * gv.w + bb.w;
    reinterpret_cast<float4*>(out + (size_t)row * DMODEL)[t] = ov;
}

extern "C" void kernel_launch(void* const* d_in, const int* in_sizes, int n_in,
                              void* d_out, int out_size, void* d_ws, size_t ws_size,
                              hipStream_t stream) {
    const float* x   = (const float*)d_in[0];
    const float* Wq  = (const float*)d_in[1];
    const float* bq  = (const float*)d_in[2];
    const float* Wk  = (const float*)d_in[3];
    const float* bk  = (const float*)d_in[4];
    const float* Wv  = (const float*)d_in[5];
    const float* bv  = (const float*)d_in[6];
    const float* Wd  = (const float*)d_in[7];
    const float* bd  = (const float*)d_in[8];
    const float* lng = (const float*)d_in[9];
    const float* lnb = (const float*)d_in[10];

    char* ws = (char*)d_ws;
    unsigned short* xb   = (unsigned short*)(ws);                    // 8 MB
    unsigned short* Wqb  = (unsigned short*)(ws + (8u  << 20));      // 2 MB each
    unsigned short* Wkb  = (unsigned short*)(ws + (10u << 20));
    unsigned short* Wvb  = (unsigned short*)(ws + (12u << 20));
    unsigned short* Wdb  = (unsigned short*)(ws + (14u << 20));
    unsigned short* Qb   = (unsigned short*)(ws + (16u << 20));      // 8 MB
    unsigned short* Kb   = (unsigned short*)(ws + (24u << 20));      // 8 MB
    unsigned short* VTb  = (unsigned short*)(ws + (32u << 20));      // 8 MB
    unsigned short* ctxb = (unsigned short*)(ws + (40u << 20));      // 8 MB
    float* proj = (float*)(ws + (16u << 20));  // 16 MB, aliases Q/K (dead after attention)

    cvt_kernel<<<4096, 256, 0, stream>>>(x,  xb,  1048576);
    cvt_kernel<<<1024, 256, 0, stream>>>(Wq, Wqb, 262144);
    cvt_kernel<<<1024, 256, 0, stream>>>(Wk, Wkb, 262144);
    cvt_kernel<<<1024, 256, 0, stream>>>(Wv, Wvb, 262144);
    cvt_kernel<<<1024, 256, 0, stream>>>(Wd, Wdb, 262144);

    gemm_qkv<<<dim3(8, 32, 3), 256, 0, stream>>>(xb, Wqb, Wkb, Wvb, bq, bk, bv, Qb, Kb, VTb);
    attn_kernel<<<dim3(32, 32), 256, 0, stream>>>(Qb, Kb, VTb, ctxb);
    gemm_proj<<<dim3(8, 32), 256, 0, stream>>>(ctxb, Wdb, bd, proj);
    ln_kernel<<<4096, 256, 0, stream>>>(proj, lng, lnb, (float*)d_out);
}